// Round 4
// baseline (1045.853 us; speedup 1.0000x reference)
//
#include <hip/hip_runtime.h>

typedef unsigned int uint;
typedef unsigned short ushort;

typedef __bf16 bf16x8 __attribute__((ext_vector_type(8)));
typedef float f32x4 __attribute__((ext_vector_type(4)));

#define AS1 __attribute__((address_space(1)))
#define AS3 __attribute__((address_space(3)))

// All d_in / d_out tensors are FP32 (per reference). Compute path is bf16
// MFMA with fp32 accumulation; x/weights are converted to bf16 up front.
__device__ __forceinline__ float bflo(uint u) { return __uint_as_float(u << 16); }
__device__ __forceinline__ float bfhi(uint u) { return __uint_as_float(u & 0xffff0000u); }
__device__ __forceinline__ ushort f2bf(float f) {
  uint u = __float_as_uint(f);
  u += 0x7fffu + ((u >> 16) & 1u);
  return (ushort)(u >> 16);
}
__device__ __forceinline__ uint pack2(float lo, float hi) {
  return (uint)f2bf(lo) | ((uint)f2bf(hi) << 16);
}

// ---------------------------------------------------------------------------
// fp32 -> bf16 elementwise cast (8 elem/thread)
// ---------------------------------------------------------------------------
__global__ __launch_bounds__(256) void cvt_f32_bf16(
    const float* __restrict__ in, ushort* __restrict__ out)
{
  const long i = ((long)blockIdx.x * 256 + threadIdx.x) * 8;
  float4 a = *(const float4*)(in + i);
  float4 b = *(const float4*)(in + i + 4);
  uint4 r;
  r.x = pack2(a.x, a.y); r.y = pack2(a.z, a.w);
  r.z = pack2(b.x, b.y); r.w = pack2(b.z, b.w);
  *(uint4*)(out + i) = r;
}

// ---------------------------------------------------------------------------
// fused transpose + fp32->bf16 cast: out[C,R](bf16) = in[R,C](fp32)^T
// ---------------------------------------------------------------------------
__global__ __launch_bounds__(256) void transpose_wf(
    const float* __restrict__ in, ushort* __restrict__ out, int R, int Ccols)
{
  __shared__ float tile[32][33];
  const int tx = threadIdx.x, ty = threadIdx.y;
  const int c0 = blockIdx.x * 32, r0 = blockIdx.y * 32;
#pragma unroll
  for (int j = 0; j < 32; j += 8)
    tile[ty + j][tx] = in[(long)(r0 + ty + j) * Ccols + (c0 + tx)];
  __syncthreads();
#pragma unroll
  for (int j = 0; j < 32; j += 8)
    out[(long)(c0 + ty + j) * R + (r0 + tx)] = f2bf(tile[tx][ty + j]);
}

// ---------------------------------------------------------------------------
// GEMM 256x256 tile, BK=64, 8 waves (2Mx4N), 8-phase schedule (HK-style):
//   per phase: {ds_read frag subtile | stage 1 half-tile via global_load_lds}
//              s_barrier; lgkmcnt(0); setprio(1); 16x mfma_16x16x32; setprio(0);
//              s_barrier.   vmcnt(4) only at phases 4/8 (counted, never 0 in loop).
// LDS 128KB: A dbuf [0,64K) (32KB per kt parity), B dbuf [64K,128K).
// XOR-swizzle (chunk ^= row&7, 16B chunks) applied on the global SOURCE address
// of global_load_lds (LDS dest stays linear) and on the ds_read address ->
// conflict-free ds_read_b128 (T2).  C[M,N] = A[M,K] @ Bt[N,K]^T + bias.
// Epilogue stages C through LDS for full-line dwordx4/float4 stores.
// ---------------------------------------------------------------------------
__global__ __launch_bounds__(512, 2) void gemm256(
    const ushort* __restrict__ A, const ushort* __restrict__ Bt,
    const float* __restrict__ bias, void* __restrict__ Cv,
    int M, int N, int K, int relu, int out_f32)
{
  __shared__ ushort lds[65536];  // 128 KiB
  const int t = threadIdx.x;
  const int w = t >> 6, l = t & 63;
  const int quad = l >> 4, l16 = l & 15;
  const int wm = w >> 2, wn = w & 3;

  // XCD-chunked swizzle (all grids used are %8==0)
  const int gx = gridDim.x;
  int bid = blockIdx.y * gx + blockIdx.x;
  const int nwg = gx * gridDim.y;
  if ((nwg & 7) == 0) bid = (bid & 7) * (nwg >> 3) + (bid >> 3);
  const long m0 = (long)(bid / gx) * 256;
  const long n0 = (long)(bid % gx) * 256;

  // ---- staging geometry ----
  // octet o = w*2 + s (16 octets of 8 rows per 16KB half-tile region)
  // A region X (mh): rows {o>>3 ? 128:0} + X*64 + (o&7)*8   (64-row bands)
  // B region Y (nh): rows (o>>2)*64 + Y*32 + (o&3)*8        (32-row bands)
  const int lr = l >> 3;       // row within octet
  const int lc = l & 7;        // 16B chunk within row
  const int swc = lc ^ lr;     // pre-swizzled source chunk (row&7 == lr)
  int arow[2][2], brow[2][2];
#pragma unroll
  for (int s = 0; s < 2; ++s) {
    const int o = w * 2 + s;
    arow[0][s] = (o >> 3) * 128 + (o & 7) * 8;
    arow[1][s] = arow[0][s] + 64;
    brow[0][s] = (o >> 2) * 64 + (o & 3) * 8;
    brow[1][s] = brow[0][s] + 32;
  }
  uint aoff[2][2], boff[2][2];
#pragma unroll
  for (int X = 0; X < 2; ++X)
#pragma unroll
    for (int s = 0; s < 2; ++s) {
      aoff[X][s] = (uint)((m0 + arow[X][s] + lr) * (long)K + swc * 8);
      boff[X][s] = (uint)((n0 + brow[X][s] + lr) * (long)K + swc * 8);
    }

#define STAGE_A(X, kt) do { \
    __builtin_amdgcn_global_load_lds((const AS1 uint*)(A + aoff[X][0] + (uint)(kt) * 64u), \
        (AS3 uint*)(lds + (((kt) & 1) << 14) + arow[X][0] * 64), 16, 0, 0); \
    __builtin_amdgcn_global_load_lds((const AS1 uint*)(A + aoff[X][1] + (uint)(kt) * 64u), \
        (AS3 uint*)(lds + (((kt) & 1) << 14) + arow[X][1] * 64), 16, 0, 0); } while (0)
#define STAGE_B(Y, kt) do { \
    __builtin_amdgcn_global_load_lds((const AS1 uint*)(Bt + boff[Y][0] + (uint)(kt) * 64u), \
        (AS3 uint*)(lds + 32768 + (((kt) & 1) << 14) + brow[Y][0] * 64), 16, 0, 0); \
    __builtin_amdgcn_global_load_lds((const AS1 uint*)(Bt + boff[Y][1] + (uint)(kt) * 64u), \
        (AS3 uint*)(lds + 32768 + (((kt) & 1) << 14) + brow[Y][1] * 64), 16, 0, 0); } while (0)

  // ---- ds_read fragment addressing (swizzled) ----
  const int rswz0 = ((0 + quad) ^ (l16 & 7)) * 8;  // ks=0
  const int rswz1 = ((4 + quad) ^ (l16 & 7)) * 8;  // ks=1
  const int abase = wm * 8192 + l16 * 64;
  const int bbase = 32768 + wn * 4096 + l16 * 64;

  bf16x8 af[4][2], b0v[2][2], b1v[2][2];

#define LDA(mh, p) do { \
  _Pragma("unroll") for (int i_ = 0; i_ < 4; ++i_) { \
    af[i_][0] = *(const bf16x8*)(lds + ((p) << 14) + abase + ((mh) * 4 + i_) * 1024 + rswz0); \
    af[i_][1] = *(const bf16x8*)(lds + ((p) << 14) + abase + ((mh) * 4 + i_) * 1024 + rswz1); } } while (0)
#define LDB(nh, p, bq) do { \
  _Pragma("unroll") for (int j_ = 0; j_ < 2; ++j_) { \
    bq[j_][0] = *(const bf16x8*)(lds + ((p) << 14) + bbase + ((nh) * 2 + j_) * 1024 + rswz0); \
    bq[j_][1] = *(const bf16x8*)(lds + ((p) << 14) + bbase + ((nh) * 2 + j_) * 1024 + rswz1); } } while (0)
#define MFMAQ(mh, nh, bq) do { \
  __builtin_amdgcn_s_setprio(1); \
  _Pragma("unroll") for (int ks_ = 0; ks_ < 2; ++ks_) \
  _Pragma("unroll") for (int i_ = 0; i_ < 4; ++i_) \
  _Pragma("unroll") for (int j_ = 0; j_ < 2; ++j_) \
    acc[(mh) * 4 + i_][(nh) * 2 + j_] = __builtin_amdgcn_mfma_f32_16x16x32_bf16( \
        af[i_][ks_], bq[j_][ks_], acc[(mh) * 4 + i_][(nh) * 2 + j_], 0, 0, 0); \
  __builtin_amdgcn_s_setprio(0); } while (0)
#define BAR() __builtin_amdgcn_s_barrier()
#define WAITLGKM() asm volatile("s_waitcnt lgkmcnt(0)" ::: "memory")
#define WAITVM(n) asm volatile("s_waitcnt vmcnt(" #n ")" ::: "memory")

  f32x4 acc[8][4];
#pragma unroll
  for (int i = 0; i < 8; ++i)
#pragma unroll
    for (int j = 0; j < 4; ++j)
      acc[i][j] = f32x4{0.f, 0.f, 0.f, 0.f};

  const int NT = K >> 6;
  const int NIT = NT >> 1;

  // prologue: t0 fully + t1's A-mh0, B-nh1 (= steady-state "prev ph7/ph8")
  STAGE_A(0, 0); STAGE_B(1, 0); STAGE_A(1, 0); STAGE_B(0, 0);
  STAGE_A(0, 1); STAGE_B(1, 1);
  WAITVM(4);
  BAR();

  for (int it = 0; it < NIT; ++it) {
    const int t1 = 2 * it + 1, t2 = 2 * it + 2, t3 = 2 * it + 3;
    const bool more = (t2 < NT);
    // ph1: q0(t0)  reads buf0 A-mh0 + B-nh0 (12 reads); stage A-mh1(t1)->buf1
    LDA(0, 0); LDB(0, 0, b0v);
    STAGE_A(1, t1);
    BAR(); WAITLGKM();
    MFMAQ(0, 0, b0v);
    BAR();
    // ph2: q1(t0)  reads B-nh1; stage B-nh0(t1)->buf1
    LDB(1, 0, b1v);
    STAGE_B(0, t1);
    BAR(); WAITLGKM();
    MFMAQ(0, 1, b1v);
    BAR();
    // ph3: q2(t0)  reads A-mh1; stage A-mh0(t2)->buf0 (A-mh0(t0) free since ph1)
    LDA(1, 0);
    if (more) STAGE_A(0, t2);
    BAR(); WAITLGKM();
    MFMAQ(1, 1, b1v);
    BAR();
    // ph4: q3(t0)  reads B-nh0; stage B-nh1(t2)->buf0; counted vmcnt -> t1 landed
    LDB(0, 0, b0v);
    if (more) STAGE_B(1, t2);
    BAR(); WAITLGKM();
    MFMAQ(1, 0, b0v);
    if (more) { WAITVM(4); } else { WAITVM(0); }
    BAR();
    // ph5: q0(t1)  reads buf1; stage A-mh1(t2)->buf0 (free since ph3)
    LDA(0, 1); LDB(0, 1, b0v);
    if (more) STAGE_A(1, t2);
    BAR(); WAITLGKM();
    MFMAQ(0, 0, b0v);
    BAR();
    // ph6: q1(t1); stage B-nh0(t2)->buf0 (free since ph4)
    LDB(1, 1, b1v);
    if (more) STAGE_B(0, t2);
    BAR(); WAITLGKM();
    MFMAQ(0, 1, b1v);
    BAR();
    // ph7: q2(t1); stage A-mh0(t3)->buf1 (A-mh0(t1) free since ph5)
    LDA(1, 1);
    if (t3 < NT) STAGE_A(0, t3);
    BAR(); WAITLGKM();
    MFMAQ(1, 1, b1v);
    BAR();
    // ph8: q3(t1); stage B-nh1(t3)->buf1 (free since ph6); vmcnt -> t2 landed
    LDB(0, 1, b0v);
    if (t3 < NT) STAGE_B(1, t3);
    BAR(); WAITLGKM();
    MFMAQ(1, 0, b0v);
    if (more) { WAITVM(4); } else { WAITVM(0); }
    BAR();
  }

  // ---- epilogue: C via LDS for coalesced full-line stores ----
  // C/D frag layout: col=l16, row=quad*4+r (verified m89/m91)
  if (!out_f32) {
    ushort* Cb = (ushort*)Cv;
#pragma unroll
    for (int hf = 0; hf < 2; ++hf) {   // 128-row halves; stride 264 (16B-aligned)
      if (wm == hf) {
#pragma unroll
        for (int in = 0; in < 4; ++in) {
          const int cl = wn * 64 + in * 16 + l16;
          const float bv = bias[n0 + cl];
#pragma unroll
          for (int im = 0; im < 8; ++im)
#pragma unroll
            for (int r = 0; r < 4; ++r) {
              float vv = acc[im][in][r] + bv;
              if (relu) vv = fmaxf(vv, 0.f);
              lds[(im * 16 + quad * 4 + r) * 264 + cl] = f2bf(vv);
            }
        }
      }
      __syncthreads();
#pragma unroll
      for (int it2 = 0; it2 < 8; ++it2) {
        const int idx = it2 * 512 + t;            // 4096 x 16B chunks = 64KB half
        const int row = idx >> 5, c16 = idx & 31; // 128 rows x 32 chunks
        uint4 d = *(const uint4*)(lds + row * 264 + c16 * 8);
        *(uint4*)(Cb + (m0 + hf * 128 + row) * (long)N + n0 + c16 * 8) = d;
      }
      __syncthreads();
    }
  } else {
    float* Cg = (float*)Cv;
    float* Cf = (float*)lds;   // [64][260] per pass
#pragma unroll
    for (int p = 0; p < 4; ++p) {      // 64-row quarters
      if (wm == (p >> 1)) {
        const int imh = p & 1;
#pragma unroll
        for (int in = 0; in < 4; ++in) {
          const int cl = wn * 64 + in * 16 + l16;
          const float bv = bias[n0 + cl];
#pragma unroll
          for (int i = 0; i < 4; ++i)
#pragma unroll
            for (int r = 0; r < 4; ++r) {
              float vv = acc[imh * 4 + i][in][r] + bv;
              if (relu) vv = fmaxf(vv, 0.f);
              Cf[(i * 16 + quad * 4 + r) * 260 + cl] = vv;
            }
        }
      }
      __syncthreads();
#pragma unroll
      for (int it2 = 0; it2 < 8; ++it2) {
        const int idx = it2 * 512 + t;            // 4096 float4 chunks
        const int row = idx >> 6, c4 = idx & 63;  // 64 rows x 64 chunks
        float4 d = *(const float4*)(Cf + row * 260 + c4 * 4);
        *(float4*)(Cg + (m0 + p * 64 + row) * (long)N + n0 + c4 * 4) = d;
      }
      __syncthreads();
    }
  }
#undef STAGE_A
#undef STAGE_B
#undef LDA
#undef LDB
#undef MFMAQ
#undef BAR
#undef WAITLGKM
#undef WAITVM
}

// ---------------------------------------------------------------------------
// MFMA window attention. One block per (b, window): 32 rows x 8 heads x 64 dh.
// 4 waves; wave w handles heads 2w, 2w+1. Phase 1: k staged in LDS, QK^T via
// mfma_16x16x32 (q frags from global), softmax in C-layout (shfl over 16-lane
// col group), P -> LDS (C-layout -> A-layout transform). Phase 2: v restaged
// over the k buffer, PV via mfma, O assembled in the P buffer (stride 72,
// 16B-aligned rows), coalesced dwordx4 store in place over q.
// ---------------------------------------------------------------------------
__global__ __launch_bounds__(256, 2) void attn_mfma(
    ushort* qo, const ushort* __restrict__ k, const ushort* __restrict__ v)
{
  __shared__ ushort kv[32 * 512];     // 32 KB: k in phase 1, v in phase 2
  __shared__ ushort pbuf[8][32 * 72]; // per (wave,head): P then O; 36 KB
  const int t = threadIdx.x;
  const int w = t >> 6, l = t & 63;
  const int quad = l >> 4, l16 = l & 15;
  const long base = (long)blockIdx.x * (32 * 512);

  // stage k -> kv (32 chunks of 1 KB = one 512-elem row each; wave-uniform base)
#pragma unroll
  for (int i = 0; i < 8; ++i) {
    const int c = w * 8 + i;
    __builtin_amdgcn_global_load_lds(
        (const AS1 uint*)(k + base + c * 512 + l * 8),
        (AS3 uint*)(kv + c * 512), 16, 0, 0);
  }
  // q fragments from global (A-layout: row=l16, k=quad*8+j), overlap k-stage
  bf16x8 qf[2][2][2];  // [hh][mt][ks]
#pragma unroll
  for (int hh = 0; hh < 2; ++hh) {
    const int h = w * 2 + hh;
#pragma unroll
    for (int mt = 0; mt < 2; ++mt)
#pragma unroll
      for (int ks = 0; ks < 2; ++ks)
        qf[hh][mt][ks] = *(const bf16x8*)(qo + base + (mt * 16 + l16) * 512 + h * 64 + ks * 32 + quad * 8);
  }
  __syncthreads();

  // QK^T + softmax + P->LDS, per head
#pragma unroll
  for (int hh = 0; hh < 2; ++hh) {
    const int h = w * 2 + hh;
    f32x4 sc[2][2];
#pragma unroll
    for (int mt = 0; mt < 2; ++mt)
#pragma unroll
      for (int nt = 0; nt < 2; ++nt)
        sc[mt][nt] = f32x4{0.f, 0.f, 0.f, 0.f};
#pragma unroll
    for (int ks = 0; ks < 2; ++ks) {
      // B-frag: B[k][n] = kmat[n][k] -> contiguous 8 elems of k-row n=l16
      bf16x8 kb0 = *(const bf16x8*)(kv + (0 * 16 + l16) * 512 + h * 64 + ks * 32 + quad * 8);
      bf16x8 kb1 = *(const bf16x8*)(kv + (1 * 16 + l16) * 512 + h * 64 + ks * 32 + quad * 8);
      sc[0][0] = __builtin_amdgcn_mfma_f32_16x16x32_bf16(qf[hh][0][ks], kb0, sc[0][0], 0, 0, 0);
      sc[0][1] = __builtin_amdgcn_mfma_f32_16x16x32_bf16(qf[hh][0][ks], kb1, sc[0][1], 0, 0, 0);
      sc[1][0] = __builtin_amdgcn_mfma_f32_16x16x32_bf16(qf[hh][1][ks], kb0, sc[1][0], 0, 0, 0);
      sc[1][1] = __builtin_amdgcn_mfma_f32_16x16x32_bf16(qf[hh][1][ks], kb1, sc[1][1], 0, 0, 0);
    }
    ushort* pb = pbuf[w * 2 + hh];
#pragma unroll
    for (int mt = 0; mt < 2; ++mt) {
#pragma unroll
      for (int r = 0; r < 4; ++r) {
        // row = mt*16 + quad*4 + r; cols nt*16+l16 (C-layout)
        float a = sc[mt][0][r] * 0.125f;  // 1/sqrt(64)
        float b = sc[mt][1][r] * 0.125f;
        float mx = fmaxf(a, b);
        mx = fmaxf(mx, __shfl_xor(mx, 1));
        mx = fmaxf(mx, __shfl_xor(mx, 2));
        mx = fmaxf(mx, __shfl_xor(mx, 4));
        mx = fmaxf(mx, __shfl_xor(mx, 8));
        float ea = __expf(a - mx), eb = __expf(b - mx);
        float s = ea + eb;
        s += __shfl_xor(s, 1);
        s += __shfl_xor(s, 2);
        s += __shfl_xor(s, 4);
        s += __shfl_xor(s, 8);
        const float inv = 1.f / s;
        const int row = mt * 16 + quad * 4 + r;
        pb[row * 72 + 0 * 16 + l16] = f2bf(ea * inv);
        pb[row * 72 + 1 * 16 + l16] = f2bf(eb * inv);
      }
    }
  }
  __syncthreads();  // all waves done reading k

  // stage v over kv
#pragma unroll
  for (int i = 0; i < 8; ++i) {
    const int c = w * 8 + i;
    __builtin_amdgcn_global_load_lds(
        (const AS1 uint*)(v + base + c * 512 + l * 8),
        (AS3 uint*)(kv + c * 512), 16, 0, 0);
  }
  // P A-frags (A-layout: row=l16+mt*16, k=quad*8+j); rows are 144B -> 16B aligned
  bf16x8 pf[2][2];  // [hh][mt]
#pragma unroll
  for (int hh = 0; hh < 2; ++hh)
#pragma unroll
    for (int mt = 0; mt < 2; ++mt)
      pf[hh][mt] = *(const bf16x8*)(pbuf[w * 2 + hh] + (mt * 16 + l16) * 72 + quad * 8);
  __syncthreads();  // v staged

#pragma unroll
  for (int hh = 0; hh < 2; ++hh) {
    const int h = w * 2 + hh;
    f32x4 oc[2][4];
#pragma unroll
    for (int mt = 0; mt < 2; ++mt)
#pragma unroll
      for (int nt = 0; nt < 4; ++nt)
        oc[mt][nt] = f32x4{0.f, 0.f, 0.f, 0.f};
#pragma unroll
    for (int nt = 0; nt < 4; ++nt) {
      // B-frag for V: B[k][n] = V[quad*8+j][h*64+nt*16+l16] (column gather)
      bf16x8 bv;
#pragma unroll
      for (int j = 0; j < 8; ++j)
        bv[j] = ((const __bf16*)kv)[(quad * 8 + j) * 512 + h * 64 + nt * 16 + l16];
      oc[0][nt] = __builtin_amdgcn_mfma_f32_16x16x32_bf16(pf[hh][0], bv, oc[0][nt], 0, 0, 0);
      oc[1][nt] = __builtin_amdgcn_mfma_f32_16x16x32_bf16(pf[hh][1], bv, oc[1][nt], 0, 0, 0);
    }
    // O -> pbuf (C-layout scatter; quad row-step 4*144B = 16 banks -> 2-way, free)
    ushort* pb = pbuf[w * 2 + hh];
#pragma unroll
    for (int mt = 0; mt < 2; ++mt)
#pragma unroll
      for (int nt = 0; nt < 4; ++nt)
#pragma unroll
        for (int r = 0; r < 4; ++r)
          pb[(mt * 16 + quad * 4 + r) * 72 + nt * 16 + l16] = f2bf(oc[mt][nt][r]);
  }

  // coalesced O store: per wave 2 heads x 32 rows x 64 cols (8 KB), in place over q.
  // Same-wave pbuf data -> no barrier needed (lgkmcnt ordering suffices).
#pragma unroll
  for (int i = 0; i < 8; ++i) {
    const int idx = i * 64 + l;           // 0..511 16B-chunks
    const int hh = idx >> 8;
    const int row = (idx >> 3) & 31;
    const int c8 = idx & 7;
    uint4 d = *(const uint4*)(pbuf[w * 2 + hh] + row * 72 + c8 * 8);
    *(uint4*)(qo + base + row * 512 + (w * 2 + hh) * 64 + c8 * 8) = d;
  }
}

// ---------------------------------------------------------------------------
// ln1: x1(bf16) = LayerNorm(a(bf16) + b(bf16)) * g + be   (rows of 512)
// one wave per row, 4 rows/block
// ---------------------------------------------------------------------------
__global__ __launch_bounds__(256, 4) void ln1_res(
    const ushort* __restrict__ a, const ushort* __restrict__ b,
    const float* __restrict__ g, const float* __restrict__ be,
    ushort* __restrict__ out)
{
  const long row = (long)blockIdx.x * 4 + (threadIdx.x >> 6);
  const int lane = threadIdx.x & 63;
  const long off = row * 512 + lane * 8;
  uint4 ua = *(const uint4*)(a + off);
  uint4 ub = *(const uint4*)(b + off);
  float x[8];
  x[0] = bflo(ua.x) + bflo(ub.x); x[1] = bfhi(ua.x) + bfhi(ub.x);
  x[2] = bflo(ua.y) + bflo(ub.y); x[3] = bfhi(ua.y) + bfhi(ub.y);
  x[4] = bflo(ua.z) + bflo(ub.z); x[5] = bfhi(ua.z) + bfhi(ub.z);
  x[6] = bflo(ua.w) + bflo(ub.w); x[7] = bfhi(ua.w) + bfhi(ub.w);
  float sum = 0.f;
#pragma unroll
  for (int i = 0; i < 8; ++i) sum += x[i];
#pragma unroll
  for (int i = 1; i < 64; i <<= 1) sum += __shfl_xor(sum, i, 64);
  const float mu = sum * (1.0f / 512.0f);
  float vsum = 0.f;
#pragma unroll
  for (int i = 0; i < 8; ++i) { const float d = x[i] - mu; vsum += d * d; }
#pragma unroll
  for (int i = 1; i < 64; i <<= 1) vsum += __shfl_xor(vsum, i, 64);
  const float rs = rsqrtf(vsum * (1.0f / 512.0f) + 1e-5f);
  float4 g0 = *(const float4*)(g + lane * 8);
  float4 g1v = *(const float4*)(g + lane * 8 + 4);
  float4 e0 = *(const float4*)(be + lane * 8);
  float4 e1 = *(const float4*)(be + lane * 8 + 4);
  uint4 r;
  r.x = pack2((x[0] - mu) * rs * g0.x + e0.x, (x[1] - mu) * rs * g0.y + e0.y);
  r.y = pack2((x[2] - mu) * rs * g0.z + e0.z, (x[3] - mu) * rs * g0.w + e0.w);
  r.z = pack2((x[4] - mu) * rs * g1v.x + e1.x, (x[5] - mu) * rs * g1v.y + e1.y);
  r.w = pack2((x[6] - mu) * rs * g1v.z + e1.z, (x[7] - mu) * rs * g1v.w + e1.w);
  *(uint4*)(out + off) = r;
}

// ---------------------------------------------------------------------------
// ln2: out(fp32) = LayerNorm(x1(bf16) + ff(fp32)) * g + be; ff aliases out
// (in-place per-thread: reads complete before writes) -> no __restrict__ on ff/out
// ---------------------------------------------------------------------------
__global__ __launch_bounds__(256, 4) void ln2_res(
    const ushort* __restrict__ a, const float* bff,
    const float* __restrict__ g, const float* __restrict__ be,
    float* out)
{
  const long row = (long)blockIdx.x * 4 + (threadIdx.x >> 6);
  const int lane = threadIdx.x & 63;
  const long off = row * 512 + lane * 8;
  uint4 ua = *(const uint4*)(a + off);
  float4 fa = *(const float4*)(bff + off);
  float4 fb = *(const float4*)(bff + off + 4);
  float x[8];
  x[0] = bflo(ua.x) + fa.x; x[1] = bfhi(ua.x) + fa.y;
  x[2] = bflo(ua.y) + fa.z; x[3] = bfhi(ua.y) + fa.w;
  x[4] = bflo(ua.z) + fb.x; x[5] = bfhi(ua.z) + fb.y;
  x[6] = bflo(ua.w) + fb.z; x[7] = bfhi(ua.w) + fb.w;
  float sum = 0.f;
#pragma unroll
  for (int i = 0; i < 8; ++i) sum += x[i];
#pragma unroll
  for (int i = 1; i < 64; i <<= 1) sum += __shfl_xor(sum, i, 64);
  const float mu = sum * (1.0f / 512.0f);
  float vsum = 0.f;
#pragma unroll
  for (int i = 0; i < 8; ++i) { const float d = x[i] - mu; vsum += d * d; }
#pragma unroll
  for (int i = 1; i < 64; i <<= 1) vsum += __shfl_xor(vsum, i, 64);
  const float rs = rsqrtf(vsum * (1.0f / 512.0f) + 1e-5f);
  float4 g0 = *(const float4*)(g + lane * 8);
  float4 g1v = *(const float4*)(g + lane * 8 + 4);
  float4 e0 = *(const float4*)(be + lane * 8);
  float4 e1 = *(const float4*)(be + lane * 8 + 4);
  float4 r0, r1;
  r0.x = (x[0] - mu) * rs * g0.x + e0.x;
  r0.y = (x[1] - mu) * rs * g0.y + e0.y;
  r0.z = (x[2] - mu) * rs * g0.z + e0.z;
  r0.w = (x[3] - mu) * rs * g0.w + e0.w;
  r1.x = (x[4] - mu) * rs * g1v.x + e1.x;
  r1.y = (x[5] - mu) * rs * g1v.y + e1.y;
  r1.z = (x[6] - mu) * rs * g1v.z + e1.z;
  r1.w = (x[7] - mu) * rs * g1v.w + e1.w;
  *(float4*)(out + off) = r0;
  *(float4*)(out + off + 4) = r1;
}

// ---------------------------------------------------------------------------
extern "C" void kernel_launch(void* const* d_in, const int* in_sizes, int n_in,
                              void* d_out, int out_size, void* d_ws, size_t ws_size,
                              hipStream_t stream)
{
  const float* x   = (const float*)d_in[0];
  const float* Wq  = (const float*)d_in[1];
  const float* bq  = (const float*)d_in[2];
  const float* Wk  = (const float*)d_in[3];
  const float* bk  = (const float*)d_in[4];
  const float* Wv  = (const float*)d_in[5];
  const float* bv  = (const float*)d_in[6];
  const float* Wo  = (const float*)d_in[7];
  const float* bo  = (const float*)d_in[8];
  const float* g1  = (const float*)d_in[9];
  const float* be1 = (const float*)d_in[10];
  const float* W1  = (const float*)d_in[11];
  const float* b1  = (const float*)d_in[12];
  const float* W2  = (const float*)d_in[13];
  const float* b2  = (const float*)d_in[14];
  const float* g2  = (const float*)d_in[15];
  const float* be2 = (const float*)d_in[16];

  const long M = 65536;               // 8 * 8192 rows
  const size_t SZ = (size_t)M * 512;  // one [M,512] activation (elements)

  // ws (bf16 units): [xb | R0 | Wqt Wkt Wvt Wot W1t W2t]  -> 134 MiB total
  ushort* wsb = (ushort*)d_ws;
  ushort* xb  = wsb;            // bf16(x); reused as FFN h buffer later
  ushort* R0  = wsb + SZ;       // q -> o -> x1
  ushort* Wqt = wsb + 2 * SZ;
  ushort* Wkt = Wqt + 512 * 512;
  ushort* Wvt = Wkt + 512 * 512;
  ushort* Wot = Wvt + 512 * 512;
  ushort* W1t = Wot + 512 * 512;   // [2048][512]
  ushort* W2t = W1t + 512 * 2048;  // [512][2048]

  // d_out (128 MiB fp32) doubles as bf16 scratch before its final contents:
  // k -> bytes [0,64M), v -> bytes [64M,128M), then attn_out over k region.
  ushort* outb = (ushort*)d_out;
  ushort* kb = outb;
  ushort* vb = outb + SZ;
  float* outf = (float*)d_out;

  dim3 tb(32, 8);
  transpose_wf<<<dim3(16, 16), tb, 0, stream>>>(Wq, Wqt, 512, 512);
  transpose_wf<<<dim3(16, 16), tb, 0, stream>>>(Wk, Wkt, 512, 512);
  transpose_wf<<<dim3(16, 16), tb, 0, stream>>>(Wv, Wvt, 512, 512);
  transpose_wf<<<dim3(16, 16), tb, 0, stream>>>(Wo, Wot, 512, 512);
  transpose_wf<<<dim3(64, 16), tb, 0, stream>>>(W1, W1t, 512, 2048);
  transpose_wf<<<dim3(16, 64), tb, 0, stream>>>(W2, W2t, 2048, 512);
  cvt_f32_bf16<<<dim3(16384), dim3(256), 0, stream>>>(x, xb);

  dim3 blk(512);
  // QKV projections (bf16 in, bf16 out); grids: (N/256, M/256), all %8==0
  gemm256<<<dim3(2, 256), blk, 0, stream>>>(xb, Wqt, bq, R0, 65536, 512, 512, 0, 0);
  gemm256<<<dim3(2, 256), blk, 0, stream>>>(xb, Wkt, bk, kb, 65536, 512, 512, 0, 0);
  gemm256<<<dim3(2, 256), blk, 0, stream>>>(xb, Wvt, bv, vb, 65536, 512, 512, 0, 0);
  // window attention (MFMA): o overwrites q in R0
  attn_mfma<<<dim3(2048), dim3(256), 0, stream>>>(R0, kb, vb);
  // attn_out = o @ Wo + bo -> outb[0,SZ) (k is dead)
  gemm256<<<dim3(2, 256), blk, 0, stream>>>(R0, Wot, bo, outb, 65536, 512, 512, 0, 0);
  // x1 = LN(x + attn_out) -> R0 (o is dead); x read as bf16 xb
  ln1_res<<<dim3(16384), dim3(256), 0, stream>>>(xb, outb, g1, be1, R0);
  // FFN in 4 row-chunks of 16384; h (bf16) fills xb exactly (16384*2048 = SZ);
  // ff (fp32) written straight into d_out rows (k/v/attn_out all dead).
  for (int c = 0; c < 4; ++c) {
    const size_t rows0 = (size_t)c * 16384;
    gemm256<<<dim3(8, 64), blk, 0, stream>>>(R0 + rows0 * 512, W1t, b1, xb,
                                             16384, 2048, 512, 1, 0);
    gemm256<<<dim3(2, 64), blk, 0, stream>>>(xb, W2t, b2, outf + rows0 * 512,
                                             16384, 512, 2048, 0, 1);
  }
  // out = LN(x1 + ff) -> fp32, in place over ff
  ln2_res<<<dim3(16384), dim3(256), 0, stream>>>(R0, outf, g2, be2, outf);
}

// Round 5
// 991.806 us; speedup vs baseline: 1.0545x; 1.0545x over previous
//
#include <hip/hip_runtime.h>

typedef unsigned int uint;
typedef unsigned short ushort;

typedef __bf16 bf16x8 __attribute__((ext_vector_type(8)));
typedef float f32x4 __attribute__((ext_vector_type(4)));

#define AS1 __attribute__((address_space(1)))
#define AS3 __attribute__((address_space(3)))

// All d_in / d_out tensors are FP32 (per reference). Compute path is bf16
// MFMA with fp32 accumulation; x/weights are converted to bf16 up front.
__device__ __forceinline__ float bflo(uint u) { return __uint_as_float(u << 16); }
__device__ __forceinline__ float bfhi(uint u) { return __uint_as_float(u & 0xffff0000u); }
__device__ __forceinline__ ushort f2bf(float f) {
  uint u = __float_as_uint(f);
  u += 0x7fffu + ((u >> 16) & 1u);
  return (ushort)(u >> 16);
}
__device__ __forceinline__ uint pack2(float lo, float hi) {
  return (uint)f2bf(lo) | ((uint)f2bf(hi) << 16);
}

// ---------------------------------------------------------------------------
// fp32 -> bf16 elementwise cast (8 elem/thread)
// ---------------------------------------------------------------------------
__global__ __launch_bounds__(256) void cvt_f32_bf16(
    const float* __restrict__ in, ushort* __restrict__ out)
{
  const long i = ((long)blockIdx.x * 256 + threadIdx.x) * 8;
  float4 a = *(const float4*)(in + i);
  float4 b = *(const float4*)(in + i + 4);
  uint4 r;
  r.x = pack2(a.x, a.y); r.y = pack2(a.z, a.w);
  r.z = pack2(b.x, b.y); r.w = pack2(b.z, b.w);
  *(uint4*)(out + i) = r;
}

// ---------------------------------------------------------------------------
// fused transpose + fp32->bf16 cast: out[C,R](bf16) = in[R,C](fp32)^T
// ---------------------------------------------------------------------------
__global__ __launch_bounds__(256) void transpose_wf(
    const float* __restrict__ in, ushort* __restrict__ out, int R, int Ccols)
{
  __shared__ float tile[32][33];
  const int tx = threadIdx.x, ty = threadIdx.y;
  const int c0 = blockIdx.x * 32, r0 = blockIdx.y * 32;
#pragma unroll
  for (int j = 0; j < 32; j += 8)
    tile[ty + j][tx] = in[(long)(r0 + ty + j) * Ccols + (c0 + tx)];
  __syncthreads();
#pragma unroll
  for (int j = 0; j < 32; j += 8)
    out[(long)(c0 + ty + j) * R + (r0 + tx)] = f2bf(tile[tx][ty + j]);
}

// ---------------------------------------------------------------------------
// GEMM 256x256 tile, BK=64, 8 waves (2Mx4N), 8-phase schedule (HK-style).
// split512 != 0: N-tiles route to 3 output planes of width 512 (QKV fusion);
// Bt is the concatenated [1536,512] weight, planes/biases selected by n0>>9.
// ---------------------------------------------------------------------------
__global__ __launch_bounds__(512, 2) void gemm256(
    const ushort* __restrict__ A, const ushort* __restrict__ Bt,
    const float* __restrict__ bias0, const float* __restrict__ bias1,
    const float* __restrict__ bias2,
    void* __restrict__ Cv0, void* __restrict__ Cv1, void* __restrict__ Cv2,
    int M, int N, int K, int relu, int out_f32, int split512)
{
  __shared__ ushort lds[65536];  // 128 KiB
  const int t = threadIdx.x;
  const int w = t >> 6, l = t & 63;
  const int quad = l >> 4, l16 = l & 15;
  const int wm = w >> 2, wn = w & 3;

  // XCD-chunked swizzle (all grids used are %8==0)
  const int gx = gridDim.x;
  int bid = blockIdx.y * gx + blockIdx.x;
  const int nwg = gx * gridDim.y;
  if ((nwg & 7) == 0) bid = (bid & 7) * (nwg >> 3) + (bid >> 3);
  const long m0 = (long)(bid / gx) * 256;
  const long n0 = (long)(bid % gx) * 256;   // global B-row base (concat space)

  // output plane / bias select (wave-uniform)
  long cn0 = n0;
  const float* bsel = bias0;
  void* Cvsel = Cv0;
  if (split512) {
    const int pi = (int)(n0 >> 9);
    cn0 = n0 & 511;
    if (pi == 1) { bsel = bias1; Cvsel = Cv1; }
    else if (pi == 2) { bsel = bias2; Cvsel = Cv2; }
  }

  // ---- staging geometry ----
  const int lr = l >> 3;       // row within octet
  const int lc = l & 7;        // 16B chunk within row
  const int swc = lc ^ lr;     // pre-swizzled source chunk (row&7 == lr)
  int arow[2][2], brow[2][2];
#pragma unroll
  for (int s = 0; s < 2; ++s) {
    const int o = w * 2 + s;
    arow[0][s] = (o >> 3) * 128 + (o & 7) * 8;
    arow[1][s] = arow[0][s] + 64;
    brow[0][s] = (o >> 2) * 64 + (o & 3) * 8;
    brow[1][s] = brow[0][s] + 32;
  }
  uint aoff[2][2], boff[2][2];
#pragma unroll
  for (int X = 0; X < 2; ++X)
#pragma unroll
    for (int s = 0; s < 2; ++s) {
      aoff[X][s] = (uint)((m0 + arow[X][s] + lr) * (long)K + swc * 8);
      boff[X][s] = (uint)((n0 + brow[X][s] + lr) * (long)K + swc * 8);
    }

#define STAGE_A(X, kt) do { \
    __builtin_amdgcn_global_load_lds((const AS1 uint*)(A + aoff[X][0] + (uint)(kt) * 64u), \
        (AS3 uint*)(lds + (((kt) & 1) << 14) + arow[X][0] * 64), 16, 0, 0); \
    __builtin_amdgcn_global_load_lds((const AS1 uint*)(A + aoff[X][1] + (uint)(kt) * 64u), \
        (AS3 uint*)(lds + (((kt) & 1) << 14) + arow[X][1] * 64), 16, 0, 0); } while (0)
#define STAGE_B(Y, kt) do { \
    __builtin_amdgcn_global_load_lds((const AS1 uint*)(Bt + boff[Y][0] + (uint)(kt) * 64u), \
        (AS3 uint*)(lds + 32768 + (((kt) & 1) << 14) + brow[Y][0] * 64), 16, 0, 0); \
    __builtin_amdgcn_global_load_lds((const AS1 uint*)(Bt + boff[Y][1] + (uint)(kt) * 64u), \
        (AS3 uint*)(lds + 32768 + (((kt) & 1) << 14) + brow[Y][1] * 64), 16, 0, 0); } while (0)

  // ---- ds_read fragment addressing (swizzled) ----
  const int rswz0 = ((0 + quad) ^ (l16 & 7)) * 8;  // ks=0
  const int rswz1 = ((4 + quad) ^ (l16 & 7)) * 8;  // ks=1
  const int abase = wm * 8192 + l16 * 64;
  const int bbase = 32768 + wn * 4096 + l16 * 64;

  bf16x8 af[4][2], b0v[2][2], b1v[2][2];

#define LDA(mh, p) do { \
  _Pragma("unroll") for (int i_ = 0; i_ < 4; ++i_) { \
    af[i_][0] = *(const bf16x8*)(lds + ((p) << 14) + abase + ((mh) * 4 + i_) * 1024 + rswz0); \
    af[i_][1] = *(const bf16x8*)(lds + ((p) << 14) + abase + ((mh) * 4 + i_) * 1024 + rswz1); } } while (0)
#define LDB(nh, p, bq) do { \
  _Pragma("unroll") for (int j_ = 0; j_ < 2; ++j_) { \
    bq[j_][0] = *(const bf16x8*)(lds + ((p) << 14) + bbase + ((nh) * 2 + j_) * 1024 + rswz0); \
    bq[j_][1] = *(const bf16x8*)(lds + ((p) << 14) + bbase + ((nh) * 2 + j_) * 1024 + rswz1); } } while (0)
#define MFMAQ(mh, nh, bq) do { \
  __builtin_amdgcn_s_setprio(1); \
  _Pragma("unroll") for (int ks_ = 0; ks_ < 2; ++ks_) \
  _Pragma("unroll") for (int i_ = 0; i_ < 4; ++i_) \
  _Pragma("unroll") for (int j_ = 0; j_ < 2; ++j_) \
    acc[(mh) * 4 + i_][(nh) * 2 + j_] = __builtin_amdgcn_mfma_f32_16x16x32_bf16( \
        af[i_][ks_], bq[j_][ks_], acc[(mh) * 4 + i_][(nh) * 2 + j_], 0, 0, 0); \
  __builtin_amdgcn_s_setprio(0); } while (0)
#define BAR() __builtin_amdgcn_s_barrier()
#define WAITLGKM() asm volatile("s_waitcnt lgkmcnt(0)" ::: "memory")
#define WAITVM(n) asm volatile("s_waitcnt vmcnt(" #n ")" ::: "memory")

  f32x4 acc[8][4];
#pragma unroll
  for (int i = 0; i < 8; ++i)
#pragma unroll
    for (int j = 0; j < 4; ++j)
      acc[i][j] = f32x4{0.f, 0.f, 0.f, 0.f};

  const int NT = K >> 6;
  const int NIT = NT >> 1;

  // prologue: t0 fully + t1's A-mh0, B-nh1 (= steady-state "prev ph7/ph8")
  STAGE_A(0, 0); STAGE_B(1, 0); STAGE_A(1, 0); STAGE_B(0, 0);
  STAGE_A(0, 1); STAGE_B(1, 1);
  WAITVM(4);
  BAR();

  for (int it = 0; it < NIT; ++it) {
    const int t1 = 2 * it + 1, t2 = 2 * it + 2, t3 = 2 * it + 3;
    const bool more = (t2 < NT);
    // ph1
    LDA(0, 0); LDB(0, 0, b0v);
    STAGE_A(1, t1);
    BAR(); WAITLGKM();
    MFMAQ(0, 0, b0v);
    BAR();
    // ph2
    LDB(1, 0, b1v);
    STAGE_B(0, t1);
    BAR(); WAITLGKM();
    MFMAQ(0, 1, b1v);
    BAR();
    // ph3
    LDA(1, 0);
    if (more) STAGE_A(0, t2);
    BAR(); WAITLGKM();
    MFMAQ(1, 1, b1v);
    BAR();
    // ph4
    LDB(0, 0, b0v);
    if (more) STAGE_B(1, t2);
    BAR(); WAITLGKM();
    MFMAQ(1, 0, b0v);
    if (more) { WAITVM(4); } else { WAITVM(0); }
    BAR();
    // ph5
    LDA(0, 1); LDB(0, 1, b0v);
    if (more) STAGE_A(1, t2);
    BAR(); WAITLGKM();
    MFMAQ(0, 0, b0v);
    BAR();
    // ph6
    LDB(1, 1, b1v);
    if (more) STAGE_B(0, t2);
    BAR(); WAITLGKM();
    MFMAQ(0, 1, b1v);
    BAR();
    // ph7
    LDA(1, 1);
    if (t3 < NT) STAGE_A(0, t3);
    BAR(); WAITLGKM();
    MFMAQ(1, 1, b1v);
    BAR();
    // ph8
    LDB(0, 1, b0v);
    if (t3 < NT) STAGE_B(1, t3);
    BAR(); WAITLGKM();
    MFMAQ(1, 0, b0v);
    if (more) { WAITVM(4); } else { WAITVM(0); }
    BAR();
  }

  // ---- epilogue: C via LDS for coalesced full-line stores ----
  // C/D frag layout: col=l16, row=quad*4+r (verified m89/m91)
  if (!out_f32) {
    ushort* Cb = (ushort*)Cvsel;
#pragma unroll
    for (int hf = 0; hf < 2; ++hf) {   // 128-row halves; stride 264 (16B-aligned)
      if (wm == hf) {
#pragma unroll
        for (int in = 0; in < 4; ++in) {
          const int cl = wn * 64 + in * 16 + l16;
          const float bv = bsel[cn0 + cl];
#pragma unroll
          for (int im = 0; im < 8; ++im)
#pragma unroll
            for (int r = 0; r < 4; ++r) {
              float vv = acc[im][in][r] + bv;
              if (relu) vv = fmaxf(vv, 0.f);
              lds[(im * 16 + quad * 4 + r) * 264 + cl] = f2bf(vv);
            }
        }
      }
      __syncthreads();
#pragma unroll
      for (int it2 = 0; it2 < 8; ++it2) {
        const int idx = it2 * 512 + t;            // 4096 x 16B chunks = 64KB half
        const int row = idx >> 5, c16 = idx & 31; // 128 rows x 32 chunks
        uint4 d = *(const uint4*)(lds + row * 264 + c16 * 8);
        *(uint4*)(Cb + (m0 + hf * 128 + row) * (long)N + cn0 + c16 * 8) = d;
      }
      __syncthreads();
    }
  } else {
    float* Cg = (float*)Cvsel;
    float* Cf = (float*)lds;   // [64][260] per pass
#pragma unroll
    for (int p = 0; p < 4; ++p) {      // 64-row quarters
      if (wm == (p >> 1)) {
        const int imh = p & 1;
#pragma unroll
        for (int in = 0; in < 4; ++in) {
          const int cl = wn * 64 + in * 16 + l16;
          const float bv = bsel[cn0 + cl];
#pragma unroll
          for (int i = 0; i < 4; ++i)
#pragma unroll
            for (int r = 0; r < 4; ++r) {
              float vv = acc[imh * 4 + i][in][r] + bv;
              if (relu) vv = fmaxf(vv, 0.f);
              Cf[(i * 16 + quad * 4 + r) * 260 + cl] = vv;
            }
        }
      }
      __syncthreads();
#pragma unroll
      for (int it2 = 0; it2 < 8; ++it2) {
        const int idx = it2 * 512 + t;            // 4096 float4 chunks
        const int row = idx >> 6, c4 = idx & 63;  // 64 rows x 64 chunks
        float4 d = *(const float4*)(Cf + row * 260 + c4 * 4);
        *(float4*)(Cg + (m0 + p * 64 + row) * (long)N + cn0 + c4 * 4) = d;
      }
      __syncthreads();
    }
  }
#undef STAGE_A
#undef STAGE_B
#undef LDA
#undef LDB
#undef MFMAQ
#undef BAR
#undef WAITLGKM
#undef WAITVM
}

// ---------------------------------------------------------------------------
// GEMM 128x128 tile (m97 structure), 4 waves, BK=64; verified round-2 version.
// Used where 256-tile grids under-fill the GPU (FFN2: grid (4,128)=512 blocks,
// 2 blocks/CU so inter-block overlap covers stage/epilogue bubbles).
// ---------------------------------------------------------------------------
#define BM 128
#define BN 128
#define BKK 64
#define CSTR 136
#define FSTR 132

__global__ __launch_bounds__(256, 2) void gemm_bt(
    const ushort* __restrict__ A, const ushort* __restrict__ Bt,
    const float* __restrict__ bias, void* __restrict__ Cv,
    int M, int N, int K, int relu, int out_f32)
{
  __shared__ ushort smem[17408];  // 34816 B
  ushort* As = smem;
  ushort* Bs = smem + BM * BKK;
  const int t = threadIdx.x;
  const int w = t >> 6, l = t & 63;
  const int quad = l >> 4, l16 = l & 15;
  const int wm = w & 1, wn = w >> 1;

  const int gx = gridDim.x;
  int bid = blockIdx.y * gx + blockIdx.x;
  const int nwg = gx * gridDim.y;
  if ((nwg & 7) == 0) bid = (bid & 7) * (nwg >> 3) + (bid >> 3);
  const long m0 = (long)(bid / gx) * BM;
  const long n0 = (long)(bid % gx) * BN;

  const int srow = l >> 3;
  const int scol = (l & 7) * 8;

  f32x4 acc[4][4];
#pragma unroll
  for (int i = 0; i < 4; ++i)
#pragma unroll
    for (int j = 0; j < 4; ++j)
      acc[i][j] = f32x4{0.f, 0.f, 0.f, 0.f};

  for (int k0 = 0; k0 < K; k0 += BKK) {
#pragma unroll
    for (int i = 0; i < 4; ++i) {
      const int chunk = w * 4 + i;
      const int row = chunk * 8 + srow;
      const ushort* ga = A + (m0 + row) * (long)K + k0 + scol;
      const ushort* gb = Bt + (n0 + row) * (long)K + k0 + scol;
      __builtin_amdgcn_global_load_lds(
          (const AS1 uint*)ga, (AS3 uint*)(As + chunk * 512), 16, 0, 0);
      __builtin_amdgcn_global_load_lds(
          (const AS1 uint*)gb, (AS3 uint*)(Bs + chunk * 512), 16, 0, 0);
    }
    __syncthreads();
#pragma unroll
    for (int ks = 0; ks < 2; ++ks) {
      bf16x8 af[4], bfr[4];
#pragma unroll
      for (int im = 0; im < 4; ++im)
        af[im] = *(const bf16x8*)(As + (wm * 64 + im * 16 + l16) * BKK + ks * 32 + quad * 8);
#pragma unroll
      for (int in = 0; in < 4; ++in)
        bfr[in] = *(const bf16x8*)(Bs + (wn * 64 + in * 16 + l16) * BKK + ks * 32 + quad * 8);
#pragma unroll
      for (int im = 0; im < 4; ++im)
#pragma unroll
        for (int in = 0; in < 4; ++in)
          acc[im][in] = __builtin_amdgcn_mfma_f32_16x16x32_bf16(af[im], bfr[in], acc[im][in], 0, 0, 0);
    }
    __syncthreads();
  }

  if (!out_f32) {
    ushort* Ct = smem;  // [128][CSTR]
#pragma unroll
    for (int in = 0; in < 4; ++in) {
      const int cl = wn * 64 + in * 16 + l16;
      const float bv = bias[n0 + cl];
#pragma unroll
      for (int im = 0; im < 4; ++im) {
        const int rl = wm * 64 + im * 16 + quad * 4;
#pragma unroll
        for (int r = 0; r < 4; ++r) {
          float vv = acc[im][in][r] + bv;
          if (relu) vv = fmaxf(vv, 0.f);
          Ct[(rl + r) * CSTR + cl] = f2bf(vv);
        }
      }
    }
    __syncthreads();
    ushort* Cb = (ushort*)Cv;
#pragma unroll
    for (int it = 0; it < 8; ++it) {
      const int idx = it * 256 + t;
      const int row = idx >> 4, c16 = idx & 15;  // 128 rows x 16 chunks
      uint4 d = *(const uint4*)(Ct + row * CSTR + c16 * 8);
      *(uint4*)(Cb + (m0 + row) * (long)N + n0 + c16 * 8) = d;
    }
  } else {
    float* Cf4 = (float*)smem;  // [64][FSTR] per half
    float* Cg = (float*)Cv;
#pragma unroll
    for (int half = 0; half < 2; ++half) {
      if (wm == half) {
#pragma unroll
        for (int in = 0; in < 4; ++in) {
          const int cl = wn * 64 + in * 16 + l16;
          const float bv = bias[n0 + cl];
#pragma unroll
          for (int im = 0; im < 4; ++im) {
            const int rl = im * 16 + quad * 4;
#pragma unroll
            for (int r = 0; r < 4; ++r) {
              float vv = acc[im][in][r] + bv;
              if (relu) vv = fmaxf(vv, 0.f);
              Cf4[(rl + r) * FSTR + cl] = vv;
            }
          }
        }
      }
      __syncthreads();
#pragma unroll
      for (int it = 0; it < 8; ++it) {
        const int idx = it * 256 + t;
        const int row = idx >> 5, c4 = idx & 31;  // 64 rows x 32 chunks
        float4 d = *(const float4*)(Cf4 + row * FSTR + c4 * 4);
        *(float4*)(Cg + (m0 + half * 64 + row) * (long)N + n0 + c4 * 4) = d;
      }
      __syncthreads();
    }
  }
}

// ---------------------------------------------------------------------------
// MFMA window attention (unchanged, verified).
// ---------------------------------------------------------------------------
__global__ __launch_bounds__(256, 2) void attn_mfma(
    ushort* qo, const ushort* __restrict__ k, const ushort* __restrict__ v)
{
  __shared__ ushort kv[32 * 512];
  __shared__ ushort pbuf[8][32 * 72];
  const int t = threadIdx.x;
  const int w = t >> 6, l = t & 63;
  const int quad = l >> 4, l16 = l & 15;
  const long base = (long)blockIdx.x * (32 * 512);

#pragma unroll
  for (int i = 0; i < 8; ++i) {
    const int c = w * 8 + i;
    __builtin_amdgcn_global_load_lds(
        (const AS1 uint*)(k + base + c * 512 + l * 8),
        (AS3 uint*)(kv + c * 512), 16, 0, 0);
  }
  bf16x8 qf[2][2][2];
#pragma unroll
  for (int hh = 0; hh < 2; ++hh) {
    const int h = w * 2 + hh;
#pragma unroll
    for (int mt = 0; mt < 2; ++mt)
#pragma unroll
      for (int ks = 0; ks < 2; ++ks)
        qf[hh][mt][ks] = *(const bf16x8*)(qo + base + (mt * 16 + l16) * 512 + h * 64 + ks * 32 + quad * 8);
  }
  __syncthreads();

#pragma unroll
  for (int hh = 0; hh < 2; ++hh) {
    const int h = w * 2 + hh;
    f32x4 sc[2][2];
#pragma unroll
    for (int mt = 0; mt < 2; ++mt)
#pragma unroll
      for (int nt = 0; nt < 2; ++nt)
        sc[mt][nt] = f32x4{0.f, 0.f, 0.f, 0.f};
#pragma unroll
    for (int ks = 0; ks < 2; ++ks) {
      bf16x8 kb0 = *(const bf16x8*)(kv + (0 * 16 + l16) * 512 + h * 64 + ks * 32 + quad * 8);
      bf16x8 kb1 = *(const bf16x8*)(kv + (1 * 16 + l16) * 512 + h * 64 + ks * 32 + quad * 8);
      sc[0][0] = __builtin_amdgcn_mfma_f32_16x16x32_bf16(qf[hh][0][ks], kb0, sc[0][0], 0, 0, 0);
      sc[0][1] = __builtin_amdgcn_mfma_f32_16x16x32_bf16(qf[hh][0][ks], kb1, sc[0][1], 0, 0, 0);
      sc[1][0] = __builtin_amdgcn_mfma_f32_16x16x32_bf16(qf[hh][1][ks], kb0, sc[1][0], 0, 0, 0);
      sc[1][1] = __builtin_amdgcn_mfma_f32_16x16x32_bf16(qf[hh][1][ks], kb1, sc[1][1], 0, 0, 0);
    }
    ushort* pb = pbuf[w * 2 + hh];
#pragma unroll
    for (int mt = 0; mt < 2; ++mt) {
#pragma unroll
      for (int r = 0; r < 4; ++r) {
        float a = sc[mt][0][r] * 0.125f;
        float b = sc[mt][1][r] * 0.125f;
        float mx = fmaxf(a, b);
        mx = fmaxf(mx, __shfl_xor(mx, 1));
        mx = fmaxf(mx, __shfl_xor(mx, 2));
        mx = fmaxf(mx, __shfl_xor(mx, 4));
        mx = fmaxf(mx, __shfl_xor(mx, 8));
        float ea = __expf(a - mx), eb = __expf(b - mx);
        float s = ea + eb;
        s += __shfl_xor(s, 1);
        s += __shfl_xor(s, 2);
        s += __shfl_xor(s, 4);
        s += __shfl_xor(s, 8);
        const float inv = 1.f / s;
        const int row = mt * 16 + quad * 4 + r;
        pb[row * 72 + 0 * 16 + l16] = f2bf(ea * inv);
        pb[row * 72 + 1 * 16 + l16] = f2bf(eb * inv);
      }
    }
  }
  __syncthreads();

#pragma unroll
  for (int i = 0; i < 8; ++i) {
    const int c = w * 8 + i;
    __builtin_amdgcn_global_load_lds(
        (const AS1 uint*)(v + base + c * 512 + l * 8),
        (AS3 uint*)(kv + c * 512), 16, 0, 0);
  }
  bf16x8 pf[2][2];
#pragma unroll
  for (int hh = 0; hh < 2; ++hh)
#pragma unroll
    for (int mt = 0; mt < 2; ++mt)
      pf[hh][mt] = *(const bf16x8*)(pbuf[w * 2 + hh] + (mt * 16 + l16) * 72 + quad * 8);
  __syncthreads();

#pragma unroll
  for (int hh = 0; hh < 2; ++hh) {
    const int h = w * 2 + hh;
    f32x4 oc[2][4];
#pragma unroll
    for (int mt = 0; mt < 2; ++mt)
#pragma unroll
      for (int nt = 0; nt < 4; ++nt)
        oc[mt][nt] = f32x4{0.f, 0.f, 0.f, 0.f};
#pragma unroll
    for (int nt = 0; nt < 4; ++nt) {
      bf16x8 bv;
#pragma unroll
      for (int j = 0; j < 8; ++j)
        bv[j] = ((const __bf16*)kv)[(quad * 8 + j) * 512 + h * 64 + nt * 16 + l16];
      oc[0][nt] = __builtin_amdgcn_mfma_f32_16x16x32_bf16(pf[hh][0], bv, oc[0][nt], 0, 0, 0);
      oc[1][nt] = __builtin_amdgcn_mfma_f32_16x16x32_bf16(pf[hh][1], bv, oc[1][nt], 0, 0, 0);
    }
    ushort* pb = pbuf[w * 2 + hh];
#pragma unroll
    for (int mt = 0; mt < 2; ++mt)
#pragma unroll
      for (int nt = 0; nt < 4; ++nt)
#pragma unroll
        for (int r = 0; r < 4; ++r)
          pb[(mt * 16 + quad * 4 + r) * 72 + nt * 16 + l16] = f2bf(oc[mt][nt][r]);
  }

#pragma unroll
  for (int i = 0; i < 8; ++i) {
    const int idx = i * 64 + l;
    const int hh = idx >> 8;
    const int row = (idx >> 3) & 31;
    const int c8 = idx & 7;
    uint4 d = *(const uint4*)(pbuf[w * 2 + hh] + row * 72 + c8 * 8);
    *(uint4*)(qo + base + row * 512 + (w * 2 + hh) * 64 + c8 * 8) = d;
  }
}

// ---------------------------------------------------------------------------
// ln1: x1(bf16) = LayerNorm(a(bf16) + b(bf16)) * g + be   (rows of 512)
// ---------------------------------------------------------------------------
__global__ __launch_bounds__(256, 4) void ln1_res(
    const ushort* __restrict__ a, const ushort* __restrict__ b,
    const float* __restrict__ g, const float* __restrict__ be,
    ushort* __restrict__ out)
{
  const long row = (long)blockIdx.x * 4 + (threadIdx.x >> 6);
  const int lane = threadIdx.x & 63;
  const long off = row * 512 + lane * 8;
  uint4 ua = *(const uint4*)(a + off);
  uint4 ub = *(const uint4*)(b + off);
  float x[8];
  x[0] = bflo(ua.x) + bflo(ub.x); x[1] = bfhi(ua.x) + bfhi(ub.x);
  x[2] = bflo(ua.y) + bflo(ub.y); x[3] = bfhi(ua.y) + bfhi(ub.y);
  x[4] = bflo(ua.z) + bflo(ub.z); x[5] = bfhi(ua.z) + bfhi(ub.z);
  x[6] = bflo(ua.w) + bflo(ub.w); x[7] = bfhi(ua.w) + bfhi(ub.w);
  float sum = 0.f;
#pragma unroll
  for (int i = 0; i < 8; ++i) sum += x[i];
#pragma unroll
  for (int i = 1; i < 64; i <<= 1) sum += __shfl_xor(sum, i, 64);
  const float mu = sum * (1.0f / 512.0f);
  float vsum = 0.f;
#pragma unroll
  for (int i = 0; i < 8; ++i) { const float d = x[i] - mu; vsum += d * d; }
#pragma unroll
  for (int i = 1; i < 64; i <<= 1) vsum += __shfl_xor(vsum, i, 64);
  const float rs = rsqrtf(vsum * (1.0f / 512.0f) + 1e-5f);
  float4 g0 = *(const float4*)(g + lane * 8);
  float4 g1v = *(const float4*)(g + lane * 8 + 4);
  float4 e0 = *(const float4*)(be + lane * 8);
  float4 e1 = *(const float4*)(be + lane * 8 + 4);
  uint4 r;
  r.x = pack2((x[0] - mu) * rs * g0.x + e0.x, (x[1] - mu) * rs * g0.y + e0.y);
  r.y = pack2((x[2] - mu) * rs * g0.z + e0.z, (x[3] - mu) * rs * g0.w + e0.w);
  r.z = pack2((x[4] - mu) * rs * g1v.x + e1.x, (x[5] - mu) * rs * g1v.y + e1.y);
  r.w = pack2((x[6] - mu) * rs * g1v.z + e1.z, (x[7] - mu) * rs * g1v.w + e1.w);
  *(uint4*)(out + off) = r;
}

// ---------------------------------------------------------------------------
// ln2: out(fp32) = LayerNorm(x1(bf16) + ff(fp32)) * g + be; ff aliases out
// ---------------------------------------------------------------------------
__global__ __launch_bounds__(256, 4) void ln2_res(
    const ushort* __restrict__ a, const float* bff,
    const float* __restrict__ g, const float* __restrict__ be,
    float* out)
{
  const long row = (long)blockIdx.x * 4 + (threadIdx.x >> 6);
  const int lane = threadIdx.x & 63;
  const long off = row * 512 + lane * 8;
  uint4 ua = *(const uint4*)(a + off);
  float4 fa = *(const float4*)(bff + off);
  float4 fb = *(const float4*)(bff + off + 4);
  float x[8];
  x[0] = bflo(ua.x) + fa.x; x[1] = bfhi(ua.x) + fa.y;
  x[2] = bflo(ua.y) + fa.z; x[3] = bfhi(ua.y) + fa.w;
  x[4] = bflo(ua.z) + fb.x; x[5] = bfhi(ua.z) + fb.y;
  x[6] = bflo(ua.w) + fb.z; x[7] = bfhi(ua.w) + fb.w;
  float sum = 0.f;
#pragma unroll
  for (int i = 0; i < 8; ++i) sum += x[i];
#pragma unroll
  for (int i = 1; i < 64; i <<= 1) sum += __shfl_xor(sum, i, 64);
  const float mu = sum * (1.0f / 512.0f);
  float vsum = 0.f;
#pragma unroll
  for (int i = 0; i < 8; ++i) { const float d = x[i] - mu; vsum += d * d; }
#pragma unroll
  for (int i = 1; i < 64; i <<= 1) vsum += __shfl_xor(vsum, i, 64);
  const float rs = rsqrtf(vsum * (1.0f / 512.0f) + 1e-5f);
  float4 g0 = *(const float4*)(g + lane * 8);
  float4 g1v = *(const float4*)(g + lane * 8 + 4);
  float4 e0 = *(const float4*)(be + lane * 8);
  float4 e1 = *(const float4*)(be + lane * 8 + 4);
  float4 r0, r1;
  r0.x = (x[0] - mu) * rs * g0.x + e0.x;
  r0.y = (x[1] - mu) * rs * g0.y + e0.y;
  r0.z = (x[2] - mu) * rs * g0.z + e0.z;
  r0.w = (x[3] - mu) * rs * g0.w + e0.w;
  r1.x = (x[4] - mu) * rs * g1v.x + e1.x;
  r1.y = (x[5] - mu) * rs * g1v.y + e1.y;
  r1.z = (x[6] - mu) * rs * g1v.z + e1.z;
  r1.w = (x[7] - mu) * rs * g1v.w + e1.w;
  *(float4*)(out + off) = r0;
  *(float4*)(out + off + 4) = r1;
}

// ---------------------------------------------------------------------------
extern "C" void kernel_launch(void* const* d_in, const int* in_sizes, int n_in,
                              void* d_out, int out_size, void* d_ws, size_t ws_size,
                              hipStream_t stream)
{
  const float* x   = (const float*)d_in[0];
  const float* Wq  = (const float*)d_in[1];
  const float* bq  = (const float*)d_in[2];
  const float* Wk  = (const float*)d_in[3];
  const float* bk  = (const float*)d_in[4];
  const float* Wv  = (const float*)d_in[5];
  const float* bv  = (const float*)d_in[6];
  const float* Wo  = (const float*)d_in[7];
  const float* bo  = (const float*)d_in[8];
  const float* g1  = (const float*)d_in[9];
  const float* be1 = (const float*)d_in[10];
  const float* W1  = (const float*)d_in[11];
  const float* b1  = (const float*)d_in[12];
  const float* W2  = (const float*)d_in[13];
  const float* b2  = (const float*)d_in[14];
  const float* g2  = (const float*)d_in[15];
  const float* be2 = (const float*)d_in[16];

  const long M = 65536;               // 8 * 8192 rows
  const size_t SZ = (size_t)M * 512;  // one [M,512] activation (elements)

  // ws (bf16 units): [xb | R0 | Wqt Wkt Wvt Wot W1t W2t]
  ushort* wsb = (ushort*)d_ws;
  ushort* xb  = wsb;            // bf16(x); reused as FFN h buffer later
  ushort* R0  = wsb + SZ;       // q -> o -> x1
  ushort* Wqt = wsb + 2 * SZ;   // [1536,512] concat: Wqt|Wkt|Wvt contiguous
  ushort* Wkt = Wqt + 512 * 512;
  ushort* Wvt = Wkt + 512 * 512;
  ushort* Wot = Wvt + 512 * 512;
  ushort* W1t = Wot + 512 * 512;   // [2048][512]
  ushort* W2t = W1t + 512 * 2048;  // [512][2048]

  // d_out doubles as bf16 scratch: k -> [0,64M), v -> [64M,128M)
  ushort* outb = (ushort*)d_out;
  ushort* kb = outb;
  ushort* vb = outb + SZ;
  float* outf = (float*)d_out;

  dim3 tb(32, 8);
  transpose_wf<<<dim3(16, 16), tb, 0, stream>>>(Wq, Wqt, 512, 512);
  transpose_wf<<<dim3(16, 16), tb, 0, stream>>>(Wk, Wkt, 512, 512);
  transpose_wf<<<dim3(16, 16), tb, 0, stream>>>(Wv, Wvt, 512, 512);
  transpose_wf<<<dim3(16, 16), tb, 0, stream>>>(Wo, Wot, 512, 512);
  transpose_wf<<<dim3(64, 16), tb, 0, stream>>>(W1, W1t, 512, 2048);
  transpose_wf<<<dim3(16, 64), tb, 0, stream>>>(W2, W2t, 2048, 512);
  cvt_f32_bf16<<<dim3(16384), dim3(256), 0, stream>>>(x, xb);

  dim3 blk(512);
  // fused QKV projection: Bt = concat [Wqt;Wkt;Wvt] (1536 rows); N-tiles route
  // to q/k/v planes of width 512. grid (6,256) = 1536 wgs, %8==0.
  gemm256<<<dim3(6, 256), blk, 0, stream>>>(xb, Wqt, bq, bk, bv,
                                            R0, kb, vb, 65536, 512, 512, 0, 0, 1);
  // window attention (MFMA): o overwrites q in R0
  attn_mfma<<<dim3(2048), dim3(256), 0, stream>>>(R0, kb, vb);
  // attn_out = o @ Wo + bo -> outb[0,SZ) (k is dead)
  gemm256<<<dim3(2, 256), blk, 0, stream>>>(R0, Wot, bo, bo, bo,
                                            outb, outb, outb, 65536, 512, 512, 0, 0, 0);
  // x1 = LN(x + attn_out) -> R0 (o is dead); x read as bf16 xb
  ln1_res<<<dim3(16384), dim3(256), 0, stream>>>(xb, outb, g1, be1, R0);
  // FFN in 4 row-chunks of 16384; h (bf16) fills xb; ff fp32 into d_out rows.
  // FFN1: gemm256 grid 512 wgs. FFN2: 128-tile gemm_bt grid (4,128)=512 wgs
  // (256-tile grid would be 128 wgs = half the CUs idle).
  for (int c = 0; c < 4; ++c) {
    const size_t rows0 = (size_t)c * 16384;
    gemm256<<<dim3(8, 64), blk, 0, stream>>>(R0 + rows0 * 512, W1t, b1, b1, b1,
                                             xb, xb, xb, 16384, 2048, 512, 1, 0, 0);
    gemm_bt<<<dim3(4, 128), dim3(256), 0, stream>>>(xb, W2t, b2, outf + rows0 * 512,
                                                    16384, 512, 2048, 0, 1);
  }
  // out = LN(x1 + ff) -> fp32, in place over ff
  ln2_res<<<dim3(16384), dim3(256), 0, stream>>>(R0, outf, g2, be2, outf);
}